// Round 5
// baseline (12.096 us; speedup 1.0000x reference)
//
#include <hip/hip_runtime.h>

// EquivariantUpSampling:
//  x: (8,128,32,32) f32, p: (8,3) int in {0,1}
//  out: (8,256,64,64) f32
//  out[b, cc*4 + f*2 + r, 2*i + p0, 2*j + p1] = rot_r(x[b, cc*2+f])[i, j]
//  where r = p[b,2], p0 = p[b,0], p1 = p[b,1]; rot_r is exact pixel-centered rot90:
//    r=0: y[i,j]   r=1: y[j,(32-i)&31]   (r>=2 unreachable: p values are in {0,1})
//  All other output elements are zero.
//
// One block == one output channel (64x64 f32 = 1024 float4); b, ch block-uniform
// -> p[] loads scalar; zero channels are a uniform fill stream. Gather channels:
// each thread owns a row pair (2q, 2q+1) x 4-col window; the data row offset
// (p0) is uniform -> zero per-lane divergence. Output stores are non-temporal
// (write-once streaming data; keep x reads cached). Native clang vector type
// for the nontemporal builtin (HIP float4 class is rejected by it).

typedef float vfloat4 __attribute__((ext_vector_type(4)));

__global__ __launch_bounds__(256) void eqs_scatter_kernel(
    const float* __restrict__ x, const int* __restrict__ p,
    vfloat4* __restrict__ out) {
    const int blk = blockIdx.x;        // 2048 blocks
    const int b   = blk >> 8;
    const int ch  = blk & 255;
    const int r   = p[b * 3 + 2];      // uniform -> s_load

    vfloat4* __restrict__ ob = out + (blk << 10);   // 1024 float4 per channel
    const int tid = threadIdx.x;
    const vfloat4 z = {0.f, 0.f, 0.f, 0.f};

    if ((ch & 1) != r) {               // uniform: whole channel is zero
        __builtin_nontemporal_store(z, ob + tid);
        __builtin_nontemporal_store(z, ob + tid + 256);
        __builtin_nontemporal_store(z, ob + tid + 512);
        __builtin_nontemporal_store(z, ob + tid + 768);
        return;
    }

    const int p0 = p[b * 3 + 0];
    const int p1 = p[b * 3 + 1];
    const float* __restrict__ xb =
        x + ((b * 128 + (ch >> 2) * 2 + ((ch >> 1) & 1)) << 10);  // 32*32

    const int jj = tid & 15;           // float4 column 0..15 (output cols 4*jj..4*jj+3)
    const int j0 = jj << 1;            // source cols j0, j0+1
    const int q0 = tid >> 4;           // row-pair index 0..15; +16 on 2nd iter
    const int sA = p0 << 4;            // uniform: float4-row offset of the data row
    const int sB = (1 - p0) << 4;      // uniform: the zero row of the pair

    #pragma unroll
    for (int it = 0; it < 2; ++it) {
        const int q = q0 + (it << 4);  // source row i = q (0..31)
        float s0, s1;
        if (r == 0) {                  // uniform branch
            s0 = xb[(q << 5) + j0];
            s1 = xb[(q << 5) + j0 + 1];
        } else {                       // r == 1
            const int col = (32 - q) & 31;
            s0 = xb[(j0 << 5) + col];
            s1 = xb[((j0 + 1) << 5) + col];
        }
        vfloat4 v = z;
        if (p1 == 0) { v.x = s0; v.z = s1; }   // uniform branch
        else         { v.y = s0; v.w = s1; }
        const int base = (q << 5) + jj;        // float4 index of row 2q, col jj
        __builtin_nontemporal_store(v, ob + base + sA);  // data row 2q+p0
        __builtin_nontemporal_store(z, ob + base + sB);  // zero row 2q+1-p0
    }
}

extern "C" void kernel_launch(void* const* d_in, const int* in_sizes, int n_in,
                              void* d_out, int out_size, void* d_ws, size_t ws_size,
                              hipStream_t stream) {
    const float* x = (const float*)d_in[0];
    const int*   p = (const int*)d_in[1];
    vfloat4* out = (vfloat4*)d_out;

    const int grid = out_size >> 12;   // one 4096-elem channel per block = 2048
    eqs_scatter_kernel<<<grid, 256, 0, stream>>>(x, p, out);
}